// Round 2
// baseline (3032.594 us; speedup 1.0000x reference)
//
#include <hip/hip_runtime.h>

#define DIMC 512   // embedding dim (fixed by the problem: 512)

// ---------------------------------------------------------------------------
// Kernel 1: base embeddings.  base[n] = data_vecs[t_n, d_n] @ data_weights[t_n]
//           + data_biases[t_n].   One block per node, 256 threads, float2/thr.
// ---------------------------------------------------------------------------
__global__ __launch_bounds__(256)
void base_kernel(const float* __restrict__ data_vecs,
                 const float* __restrict__ data_weights,
                 const float* __restrict__ data_biases,
                 const int* __restrict__ data,
                 const int* __restrict__ types,
                 float* __restrict__ base,
                 int V, int VD) {
  const int n = blockIdx.x;
  const int t = threadIdx.x;
  __shared__ float sel[DIMC];
  const int ty = types[n];
  const long long idx = data[n];
  const float* src = data_vecs + ((long long)ty * V + idx) * VD;
  for (int d = t; d < VD; d += 256) sel[d] = src[d];
  __syncthreads();
  const float* W = data_weights + (long long)ty * VD * DIMC;
  const int f0 = 2 * t;
  float2 a = {0.f, 0.f};
  for (int d = 0; d < VD; ++d) {
    const float s = sel[d];
    const float2 w = *(const float2*)(W + (long long)d * DIMC + f0);
    a.x = fmaf(s, w.x, a.x);
    a.y = fmaf(s, w.y, a.y);
  }
  const float* b = data_biases + (long long)ty * DIMC;
  base[(long long)n * DIMC + f0]     = a.x + b[f0];
  base[(long long)n * DIMC + f0 + 1] = a.y + b[f0 + 1];
}

// ---------------------------------------------------------------------------
// Kernel 2: per-graph topology analysis (on device: no host readback allowed).
//   One thread per graph.  Produces: parents (post root-chain), child counts,
//   1/denom, height-sorted node order, pos-ancestor path, root edge id.
// ---------------------------------------------------------------------------
__global__ void setup_kernel(const int* __restrict__ graphs,
                             const int* __restrict__ edges,
                             const int* __restrict__ pos_p,
                             int* __restrict__ par, int* __restrict__ nch,
                             int* __restrict__ hh, int* __restrict__ onp,
                             int* __restrict__ plist, int* __restrict__ ord,
                             int* __restrict__ plen, int* __restrict__ eroot,
                             float* __restrict__ inv_denom,
                             int G, int N) {
  const int g = blockIdx.x * blockDim.x + threadIdx.x;
  if (g >= G) return;
  const int pos = *pos_p;
  int* P = par + g * N;
  int* C = nch + g * N;
  int* H = hh + g * N;
  int* O = onp + g * N;
  int* L = plist + g * N;
  int* ORD = ord + g * N;
  for (int c = 0; c < N; ++c) { P[c] = graphs[g * N + c]; C[c] = 0; H[c] = 0; O[c] = 0; }
  // roots: chain multiple roots, last becomes THE root (faithful to reference)
  int prev = -1;
  for (int i = 0; i < N; ++i)
    if (P[i] == i) { if (prev >= 0) P[prev] = i; prev = i; }
  const int root = prev;
  P[root] = -1;  // sentinel (reference uses -n)
  for (int c = 0; c < N; ++c) { const int p = P[c]; if (p >= 0) C[p]++; }
  int internal = 0;
  for (int c = 0; c < N; ++c) if (C[c] > 0) internal++;
  inv_denom[g] = 1.0f / (float)(internal + 1);
  // heights (longest path to leaf) by relaxation (loop guards chained-root case)
  for (int it = 0; it < N; ++it) {
    bool changed = false;
    for (int c = N - 1; c >= 0; --c) {
      const int p = P[c];
      if (p >= 0 && H[c] + 1 > H[p]) { H[p] = H[c] + 1; changed = true; }
    }
    if (!changed) break;
  }
  int mh = 0;
  for (int c = 0; c < N; ++c) mh = max(mh, H[c]);
  // height-ascending (stable) processing order: children always before parents
  int idx = 0;
  for (int h = 0; h <= mh; ++h)
    for (int c = 0; c < N; ++c)
      if (H[c] == h) ORD[idx++] = c;
  // ancestor path of pos (strict ancestors, bottom-up, ends at root)
  int pl = 0;
  int x = (pos == root) ? -1 : P[pos];
  while (x >= 0) { L[pl++] = x; O[x] = 1; x = P[x]; }
  plen[g] = pl;
  eroot[g] = (root == pos) ? -1 : edges[root];
}

// ---------------------------------------------------------------------------
// Kernel 3: fold final projection + score into u[g] = W[e_root] @ sw (per d),
//           c0[g] = b[e_root] . sw.    One block (512 thr) per graph.
// ---------------------------------------------------------------------------
__global__ __launch_bounds__(512)
void score_prep_kernel(const float* __restrict__ ew, const float* __restrict__ eb,
                       const float* __restrict__ sw_g,
                       const int* __restrict__ eroot,
                       float* __restrict__ u, float* __restrict__ c0) {
  const int g = blockIdx.x;
  const int t = threadIdx.x;
  __shared__ float sw[DIMC];
  __shared__ float red[DIMC];
  sw[t] = sw_g[t];
  __syncthreads();
  const int er = eroot[g];
  if (er < 0) { if (t == 0) c0[g] = 0.f; return; }  // pos==root fallback
  const float* row = ew + (long long)er * DIMC * DIMC + (long long)t * DIMC;
  float a = 0.f;
  for (int f = 0; f < DIMC; ++f) a = fmaf(row[f], sw[f], a);
  u[(long long)g * DIMC + t] = a;
  red[t] = eb[(long long)er * DIMC + t] * sw[t];
  __syncthreads();
  for (int s = 256; s > 0; s >>= 1) {
    if (t < s) red[t] += red[t + s];
    __syncthreads();
  }
  if (t == 0) c0[g] = red[0];
}

// ---------------------------------------------------------------------------
// Kernel 4: scalar tree pass — ONE BLOCK PER GRAPH, no cross-block sync.
//   Nodes processed in height-ascending order (children before parents).
//   1024 threads: 4 groups of 256 split the K=512 contraction; LDS reduce.
//   Path-ancestor nodes are skipped (finalized per-e in pass 2); pos itself is
//   finalized here (its subtree is scalar) but contributes only in pass 2.
// ---------------------------------------------------------------------------
__global__ __launch_bounds__(1024)
void pass1_kernel(const float* __restrict__ base, float* __restrict__ epos,
                  float* __restrict__ acc,
                  const float* __restrict__ ew, const float* __restrict__ eb,
                  const int* __restrict__ par, const int* __restrict__ nch,
                  const int* __restrict__ ord, const int* __restrict__ onp,
                  const int* __restrict__ edges, const float* __restrict__ invd,
                  const int* __restrict__ pos_p, int N) {
  const int g = blockIdx.x;
  const int t = threadIdx.x;
  const int dg = t >> 8;        // 0..3 : which quarter of the contraction dim
  const int tf = t & 255;
  const int f0 = 2 * tf;
  __shared__ float v[DIMC];
  __shared__ float part[4 * DIMC];
  const int pos = *pos_p;
  const float inv = invd[g];
  for (int k = 0; k < N; ++k) {
    const int c = ord[g * N + k];
    if (onp[g * N + c]) continue;            // block-uniform skip (path node)
    const int pr = par[g * N + c];
    const bool is_pos = (c == pos);
    if (dg == 0) {                           // finalize node c into LDS v
      const float* bs = base + (long long)c * DIMC;
      float2 val;
      if (nch[g * N + c] == 0) {             // leaf: no relu, no divide
        val.x = bs[f0]; val.y = bs[f0 + 1];
      } else {
        const float* ac = acc + ((long long)g * N + c) * DIMC;
        val.x = fmaxf((bs[f0] + ac[f0]) * inv, 0.f);
        val.y = fmaxf((bs[f0 + 1] + ac[f0 + 1]) * inv, 0.f);
      }
      if (is_pos) {
        epos[(long long)g * DIMC + f0]     = val.x;
        epos[(long long)g * DIMC + f0 + 1] = val.y;
      }
      v[f0] = val.x; v[f0 + 1] = val.y;
    }
    __syncthreads();
    const bool contrib = (!is_pos) && (pr >= 0);
    if (contrib) {                           // partial matvec over 128 of 512 d
      const int e = edges[c];
      const int d0 = dg << 7;
      const float* W = ew + (long long)e * DIMC * DIMC + (long long)d0 * DIMC;
      float2 a = {0.f, 0.f};
      for (int d = 0; d < 128; ++d) {
        const float s = v[d0 + d];
        const float2 w = *(const float2*)(W + (long long)d * DIMC + f0);
        a.x = fmaf(s, w.x, a.x);
        a.y = fmaf(s, w.y, a.y);
      }
      part[dg * DIMC + f0]     = a.x;
      part[dg * DIMC + f0 + 1] = a.y;
    }
    __syncthreads();
    if (contrib && dg == 0) {                // reduce 4 partials, add into parent
      const int e = edges[c];
      float sx = part[f0] + part[DIMC + f0] + part[2 * DIMC + f0] + part[3 * DIMC + f0];
      float sy = part[f0 + 1] + part[DIMC + f0 + 1] + part[2 * DIMC + f0 + 1]
               + part[3 * DIMC + f0 + 1];
      float* ac = acc + ((long long)g * N + pr) * DIMC;
      ac[f0]     += sx + eb[(long long)e * DIMC + f0];
      ac[f0 + 1] += sy + eb[(long long)e * DIMC + f0 + 1];
    }
    __syncthreads();                          // protect v/part before next node
  }
}

// ---------------------------------------------------------------------------
// Kernel 5: path pass.  One block per (g,e): walk the pos-ancestor chain,
// one matvec + relu per step, then epilogue dot with u[g].
// ---------------------------------------------------------------------------
struct P2Args {
  const float* base; const float* epos; const float* acc;
  const float* ew; const float* eb; const float* sw;
  const float* u; const float* c0; const float* inv_denom;
  const int* plist; const int* plen; const int* edges; const int* pos_p;
  float* out; int G, N, E;
};

__global__ __launch_bounds__(256)
void pass2_kernel(P2Args p) {
  const int g = blockIdx.x / p.E;
  const int e = blockIdx.x - g * p.E;
  const int t = threadIdx.x;
  const int f0 = 2 * t;
  __shared__ float ce[DIMC];
  __shared__ float red[256];
  const float* es = p.epos + (long long)g * DIMC;
  ce[f0] = es[f0]; ce[f0 + 1] = es[f0 + 1];
  __syncthreads();
  const int pl = p.plen[g];
  const float inv = p.inv_denom[g];
  for (int s = 0; s < pl; ++s) {
    const int pnode = p.plist[g * p.N + s];
    const int we = (s == 0) ? e : p.edges[p.plist[g * p.N + s - 1]];
    const float* W = p.ew + (long long)we * DIMC * DIMC;
    float2 a = {0.f, 0.f};
    for (int d = 0; d < DIMC; ++d) {
      const float sv = ce[d];
      const float2 w = *(const float2*)(W + (long long)d * DIMC + f0);
      a.x = fmaf(sv, w.x, a.x);
      a.y = fmaf(sv, w.y, a.y);
    }
    a.x += p.eb[(long long)we * DIMC + f0];
    a.y += p.eb[(long long)we * DIMC + f0 + 1];
    const float* bs = p.base + (long long)pnode * DIMC;
    const float* ac = p.acc + ((long long)g * p.N + pnode) * DIMC;
    a.x = fmaxf((a.x + bs[f0] + ac[f0]) * inv, 0.f);
    a.y = fmaxf((a.y + bs[f0 + 1] + ac[f0 + 1]) * inv, 0.f);
    __syncthreads();
    ce[f0] = a.x; ce[f0 + 1] = a.y;
    __syncthreads();
  }
  float partial;
  if (pl > 0) {
    const float* ug = p.u + (long long)g * DIMC;
    partial = ce[f0] * ug[f0] + ce[f0 + 1] * ug[f0 + 1];
  } else {
    // pos == root: final = ce @ W_e + b_e, score = final . sw  (general fallback)
    const float* W = p.ew + (long long)e * DIMC * DIMC;
    float2 a = {0.f, 0.f};
    for (int d = 0; d < DIMC; ++d) {
      const float sv = ce[d];
      const float2 w = *(const float2*)(W + (long long)d * DIMC + f0);
      a.x = fmaf(sv, w.x, a.x);
      a.y = fmaf(sv, w.y, a.y);
    }
    a.x += p.eb[(long long)e * DIMC + f0];
    a.y += p.eb[(long long)e * DIMC + f0 + 1];
    partial = a.x * p.sw[f0] + a.y * p.sw[f0 + 1];
  }
  red[t] = partial;
  __syncthreads();
  for (int s2 = 128; s2 > 0; s2 >>= 1) {
    if (t < s2) red[t] += red[t + s2];
    __syncthreads();
  }
  if (t == 0) {
    float res = red[0] + ((pl > 0) ? p.c0[g] : 0.f);
    p.out[(long long)g * p.E + e] = res;
  }
}

// ---------------------------------------------------------------------------
extern "C" void kernel_launch(void* const* d_in, const int* in_sizes, int n_in,
                              void* d_out, int out_size, void* d_ws, size_t ws_size,
                              hipStream_t stream) {
  const float* data_vecs    = (const float*)d_in[0];
  const float* data_weights = (const float*)d_in[1];
  const float* data_biases  = (const float*)d_in[2];
  const float* edge_weights = (const float*)d_in[3];
  const float* edge_biases  = (const float*)d_in[4];
  const float* score_w      = (const float*)d_in[5];
  const int*   data   = (const int*)d_in[6];
  const int*   types  = (const int*)d_in[7];
  const int*   graphs = (const int*)d_in[8];
  const int*   edges  = (const int*)d_in[9];
  const int*   pos_p  = (const int*)d_in[10];

  const int DIM = in_sizes[5];              // 512 (score_weights is DIM x 1)
  const int T   = in_sizes[2] / DIM;        // 2
  const int E   = in_sizes[4] / DIM;        // 64
  const int N   = in_sizes[6];              // 128
  const int G   = in_sizes[8] / N;          // 16
  const int VD  = in_sizes[1] / (T * DIM);  // 512
  const int V   = in_sizes[0] / (T * VD);   // 100000
  (void)DIM; (void)n_in; (void)ws_size; (void)out_size;

  // ---- workspace carving (floats first, then int metadata) ----
  char* w = (char*)d_ws;
  float* base = (float*)w;      w += (size_t)N * DIMC * sizeof(float);
  float* epos = (float*)w;      w += (size_t)G * DIMC * sizeof(float);
  float* acc  = (float*)w;      w += (size_t)G * N * DIMC * sizeof(float);
  float* u    = (float*)w;      w += (size_t)G * DIMC * sizeof(float);
  float* c0   = (float*)w;      w += (size_t)G * sizeof(float);
  float* invd = (float*)w;      w += (size_t)G * sizeof(float);
  int* par    = (int*)w;        w += (size_t)G * N * sizeof(int);
  int* nch    = (int*)w;        w += (size_t)G * N * sizeof(int);
  int* hh     = (int*)w;        w += (size_t)G * N * sizeof(int);
  int* onp    = (int*)w;        w += (size_t)G * N * sizeof(int);
  int* plist  = (int*)w;        w += (size_t)G * N * sizeof(int);
  int* ordb   = (int*)w;        w += (size_t)G * N * sizeof(int);
  int* plen   = (int*)w;        w += (size_t)G * sizeof(int);
  int* eroot  = (int*)w;        w += (size_t)G * sizeof(int);

  // acc must start at zero (ws is poisoned 0xAA before every launch)
  hipMemsetAsync(acc, 0, (size_t)G * N * DIMC * sizeof(float), stream);

  base_kernel<<<N, 256, 0, stream>>>(data_vecs, data_weights, data_biases,
                                     data, types, base, V, VD);

  setup_kernel<<<1, 64, 0, stream>>>(graphs, edges, pos_p,
                                     par, nch, hh, onp, plist, ordb,
                                     plen, eroot, invd, G, N);

  score_prep_kernel<<<G, 512, 0, stream>>>(edge_weights, edge_biases, score_w,
                                           eroot, u, c0);

  pass1_kernel<<<G, 1024, 0, stream>>>(base, epos, acc,
                                       edge_weights, edge_biases,
                                       par, nch, ordb, onp, edges, invd,
                                       pos_p, N);

  P2Args p2;
  p2.base = base; p2.epos = epos; p2.acc = acc;
  p2.ew = edge_weights; p2.eb = edge_biases; p2.sw = score_w;
  p2.u = u; p2.c0 = c0; p2.inv_denom = invd;
  p2.plist = plist; p2.plen = plen; p2.edges = edges; p2.pos_p = pos_p;
  p2.out = (float*)d_out; p2.G = G; p2.N = N; p2.E = E;
  pass2_kernel<<<G * E, 256, 0, stream>>>(p2);
}